// Round 12
// baseline (547.684 us; speedup 1.0000x reference)
//
#include <hip/hip_runtime.h>

typedef unsigned short u16;
typedef unsigned int   u32;

using sx8   = __attribute__((ext_vector_type(8))) short;   // 8 x bf16 bits
using f32x4 = __attribute__((ext_vector_type(4))) float;
using u16x8 = __attribute__((ext_vector_type(8))) unsigned short;

#define BB 4
#define TT 2048
#define CC 2048
#define HH 16
#define DD 128
#define FF 6144
#define MM 8192

static __device__ __forceinline__ u16 f2bf(float f) {
    u32 u = __builtin_bit_cast(u32, f);
    u32 lsb = (u >> 16) & 1u;
    u += 0x7fffu + lsb;
    return (u16)(u >> 16);
}
static __device__ __forceinline__ float bf2f(u16 b) {
    return __builtin_bit_cast(float, (u32)b << 16);
}
static __device__ __forceinline__ f32x4 mfma16(sx8 a, sx8 b, f32x4 c) {
    return __builtin_amdgcn_mfma_f32_16x16x32_bf16(a, b, c, 0, 0, 0);
}
static __device__ __forceinline__ u32 pkbf(float a, float b) {
    return (u32)f2bf(a) | ((u32)f2bf(b) << 16);
}

// ---------------- f32 -> bf16 convert, 8 elems/thread ----------------
__global__ __launch_bounds__(256) void k_cvt(const float* __restrict__ src,
                                             u16* __restrict__ dst, int n8) {
    int i = blockIdx.x * 256 + threadIdx.x;
    if (i >= n8) return;
    const float4* s = (const float4*)src;
    float4 a = s[2 * (size_t)i], b = s[2 * (size_t)i + 1];
    u16x8 r;
    r[0] = f2bf(a.x); r[1] = f2bf(a.y); r[2] = f2bf(a.z); r[3] = f2bf(a.w);
    r[4] = f2bf(b.x); r[5] = f2bf(b.y); r[6] = f2bf(b.z); r[7] = f2bf(b.w);
    *(u16x8*)(dst + 8 * (size_t)i) = r;
}

// ---------------- bf16 A(MxK) @ Bt(NxK)^T GEMM — 8-phase m201-style ----------------
// 256x256 tile, BK=64, 512 threads (8 waves 2Mx4N), 2 full-tile double buffers
// (128 KB), half-tile staging stream [B-lo,B-hi,A-lo,A-hi] one half per phase,
// 4 phases/K-tile: {stage || ds_read subtile -> barrier -> lgkmcnt(0) ->
// setprio MFMA x16 -> barrier}, ONE counted vmcnt(4) per tile (0 only at tail).
// XOR granule swizzle g^=(row&7) both sides -> 2-way max (free).
template <int OUTF32>
__global__ __launch_bounds__(512, 2) void k_gemm(const u16* __restrict__ A,
                                                 const u16* __restrict__ Bt,
                                                 float* __restrict__ Cf,
                                                 u16* __restrict__ Cb,
                                                 int M, int N, int K) {
    __shared__ __align__(16) u16 sA[2][16384];   // 64 KB: [buf][half*8192 + row*64 + g*8]
    __shared__ __align__(16) u16 sB[2][16384];   // 64 KB
    const int nbm = M >> 8;
    const int rpx = nbm >> 3;
    const int fid = blockIdx.x;
    const int xcd = fid & 7, idx = fid >> 3;
    const int m0 = (xcd * rpx + (idx % rpx)) << 8;   // XCD-clustered, m fastest
    const int n0 = (idx / rpx) << 8;

    const int tid = threadIdx.x, w = tid >> 6, l = tid & 63;
    const int wm = w >> 2, wn = w & 3;               // wave -> 128x64 output tile
    const int lr = l & 15, lg = l >> 4;
    const int nk = K >> 6;                           // BK=64

    // staging: wave w covers rows 16w..16w+15 of a half; 2 GLL (8 rows each).
    // dest is linear (base + lane*16B); source granule pre-swizzled.
    const int sg = (l & 7) ^ (l >> 3);               // source 16B-granule
    const u16* gA = A  + (size_t)(m0 + w * 16 + (l >> 3)) * K + sg * 8;
    const u16* gB = Bt + (size_t)(n0 + w * 16 + (l >> 3)) * K + sg * 8;
    const size_t rowK8 = (size_t)8 * K;
    const size_t halfK = (size_t)128 * K;

#define GLL(SRC, DST) __builtin_amdgcn_global_load_lds( \
        (const __attribute__((address_space(1))) void*)(SRC), \
        (__attribute__((address_space(3))) void*)(DST), 16, 0, 0)
#define STAGE_A(tt, hf) do { \
        const u16* _s = gA + (size_t)(hf) * halfK + (size_t)(tt) * 64; \
        u16* _d = &sA[(tt) & 1][(hf) * 8192 + w * 1024]; \
        GLL(_s, _d); GLL(_s + rowK8, _d + 512); } while (0)
#define STAGE_B(tt, hf) do { \
        const u16* _s = gB + (size_t)(hf) * halfK + (size_t)(tt) * 64; \
        u16* _d = &sB[(tt) & 1][(hf) * 8192 + w * 1024]; \
        GLL(_s, _d); GLL(_s + rowK8, _d + 512); } while (0)

    // read-side offsets (u16 idx). LDS[row][g] holds global granule g^(row&7).
    const int rx = lr & 7;
    const int rsw0 = ((0 + lg) ^ rx) * 8;            // ks0: G = lg
    const int rsw1 = ((4 + lg) ^ rx) * 8;            // ks1: G = 4+lg
    const int aoff0 = wm * 8192 + lr * 64 + rsw0;    // + mi*1024
    const int aoff1 = wm * 8192 + lr * 64 + rsw1;
    const int boff0 = (wn >> 1) * 8192 + ((wn & 1) * 64 + lr) * 64 + rsw0;   // + ni*1024
    const int boff1 = (wn >> 1) * 8192 + ((wn & 1) * 64 + lr) * 64 + rsw1;

    f32x4 acc[8][4] = {};

    // prologue: stream halves s=0..5 = t0.{Blo,Bhi,Alo,Ahi}, t1.{Blo,Bhi}
    STAGE_B(0, 0); STAGE_B(0, 1); STAGE_A(0, 0); STAGE_A(0, 1);
    STAGE_B(1, 0); STAGE_B(1, 1);
    asm volatile("s_waitcnt vmcnt(4)" ::: "memory");   // t0 landed; t1.B in flight
    __builtin_amdgcn_s_barrier();

#pragma unroll 1
    for (int t = 0; t < nk; ++t) {
        const u16* bA = sA[t & 1];
        const u16* bB = sB[t & 1];
        sx8 a0[8], a1[8], b0[4], b1[4];
        // ---- phase 0: stage (t+1).A-lo; read A-ks0 + B-ks0; MFMA ks0 x ni01 ----
        if (t + 1 < nk) STAGE_A(t + 1, 0);
#pragma unroll
        for (int mi = 0; mi < 8; ++mi) a0[mi] = *(const sx8*)(bA + aoff0 + mi * 1024);
#pragma unroll
        for (int ni = 0; ni < 4; ++ni) b0[ni] = *(const sx8*)(bB + boff0 + ni * 1024);
        __builtin_amdgcn_s_barrier();
        asm volatile("s_waitcnt lgkmcnt(0)" ::: "memory");
        __builtin_amdgcn_sched_barrier(0);
        __builtin_amdgcn_s_setprio(1);
#pragma unroll
        for (int mi = 0; mi < 8; ++mi) {
            acc[mi][0] = mfma16(a0[mi], b0[0], acc[mi][0]);
            acc[mi][1] = mfma16(a0[mi], b0[1], acc[mi][1]);
        }
        __builtin_amdgcn_s_setprio(0);
        __builtin_amdgcn_s_barrier();
        // ---- phase 1: stage (t+1).A-hi; read B-ks1; MFMA ks0 x ni23 ----
        if (t + 1 < nk) STAGE_A(t + 1, 1);
#pragma unroll
        for (int ni = 0; ni < 4; ++ni) b1[ni] = *(const sx8*)(bB + boff1 + ni * 1024);
        __builtin_amdgcn_s_barrier();
        asm volatile("s_waitcnt lgkmcnt(0)" ::: "memory");
        __builtin_amdgcn_sched_barrier(0);
        __builtin_amdgcn_s_setprio(1);
#pragma unroll
        for (int mi = 0; mi < 8; ++mi) {
            acc[mi][2] = mfma16(a0[mi], b0[2], acc[mi][2]);
            acc[mi][3] = mfma16(a0[mi], b0[3], acc[mi][3]);
        }
        __builtin_amdgcn_s_setprio(0);
        __builtin_amdgcn_s_barrier();
        // ---- phase 2: stage (t+2).B-lo; read A-ks1; MFMA ks1 x ni01 ----
        if (t + 2 < nk) STAGE_B(t + 2, 0);
#pragma unroll
        for (int mi = 0; mi < 8; ++mi) a1[mi] = *(const sx8*)(bA + aoff1 + mi * 1024);
        __builtin_amdgcn_s_barrier();
        asm volatile("s_waitcnt lgkmcnt(0)" ::: "memory");
        __builtin_amdgcn_sched_barrier(0);
        __builtin_amdgcn_s_setprio(1);
#pragma unroll
        for (int mi = 0; mi < 8; ++mi) {
            acc[mi][0] = mfma16(a1[mi], b1[0], acc[mi][0]);
            acc[mi][1] = mfma16(a1[mi], b1[1], acc[mi][1]);
        }
        __builtin_amdgcn_s_setprio(0);
        __builtin_amdgcn_s_barrier();
        // ---- phase 3: stage (t+2).B-hi; MFMA ks1 x ni23; boundary vmcnt ----
        if (t + 2 < nk) STAGE_B(t + 2, 1);
        __builtin_amdgcn_s_barrier();
        asm volatile("s_waitcnt lgkmcnt(0)" ::: "memory");
        __builtin_amdgcn_sched_barrier(0);
        __builtin_amdgcn_s_setprio(1);
#pragma unroll
        for (int mi = 0; mi < 8; ++mi) {
            acc[mi][2] = mfma16(a1[mi], b1[2], acc[mi][2]);
            acc[mi][3] = mfma16(a1[mi], b1[3], acc[mi][3]);
        }
        __builtin_amdgcn_s_setprio(0);
        if (t + 2 < nk) asm volatile("s_waitcnt vmcnt(4)" ::: "memory");
        else            asm volatile("s_waitcnt vmcnt(0)" ::: "memory");
        __builtin_amdgcn_s_barrier();
    }
#undef STAGE_A
#undef STAGE_B
#undef GLL

    // epilogue: D row = (lane>>4)*4+reg, col = lane&15
#pragma unroll
    for (int mi = 0; mi < 8; ++mi) {
        const int mr = m0 + wm * 128 + mi * 16 + lg * 4;
#pragma unroll
        for (int ni = 0; ni < 4; ++ni) {
            const int nc = n0 + wn * 64 + ni * 16 + lr;
#pragma unroll
            for (int rg = 0; rg < 4; ++rg) {
                float v = acc[mi][ni][rg];
                size_t off = (size_t)(mr + rg) * N + nc;
                if (OUTF32) Cf[off] = v;
                else        Cb[off] = f2bf(v);
            }
        }
    }
}

// ---------------- RoPE + split qkv -> Q,K (b,h,t,d) and V^T (b,h,d,t) ----------------
// Q is pre-scaled by 1/sqrt(D) here (free), so k_attn skips the scale multiply.
__global__ __launch_bounds__(256) void k_rope(const u16* __restrict__ qkv,
                                              const float* __restrict__ freqs,
                                              u16* __restrict__ Qo,
                                              u16* __restrict__ Ko,
                                              u16* __restrict__ Vt) {
    const int t0 = blockIdx.x * 64, h = blockIdx.y, b = blockIdx.z;
    const int tid = threadIdx.x;
    const float scale = 0.08838834764831845f;   // 1/sqrt(128)
    __shared__ u16 vt[64][129];
#pragma unroll
    for (int it = 0; it < 16; ++it) {
        int idx = tid + it * 256;
        int trow = idx >> 6, pr = idx & 63;
        int t = t0 + trow;
        size_t ib = (size_t)(b * TT + t) * FF + h * DD + 2 * pr;
        float2 cs = *(const float2*)(freqs + (size_t)t * DD + 2 * pr);
        size_t ob = ((size_t)(b * HH + h) * TT + t) * DD + 2 * pr;
        {
            u32 qp = *(const u32*)(qkv + ib);
            float x0 = bf2f((u16)(qp & 0xffff)), x1 = bf2f((u16)(qp >> 16));
            u32 r = (u32)f2bf((x0 * cs.x - x1 * cs.y) * scale) |
                    ((u32)f2bf((x0 * cs.y + x1 * cs.x) * scale) << 16);
            *(u32*)(Qo + ob) = r;
        }
        {
            u32 kp = *(const u32*)(qkv + ib + CC);
            float x0 = bf2f((u16)(kp & 0xffff)), x1 = bf2f((u16)(kp >> 16));
            u32 r = (u32)f2bf(x0 * cs.x - x1 * cs.y) |
                    ((u32)f2bf(x0 * cs.y + x1 * cs.x) << 16);
            *(u32*)(Ko + ob) = r;
        }
        {
            u32 vp = *(const u32*)(qkv + ib + 2 * CC);
            vt[trow][2 * pr]     = (u16)(vp & 0xffff);
            vt[trow][2 * pr + 1] = (u16)(vp >> 16);
        }
    }
    __syncthreads();
    const size_t vb = (size_t)(b * HH + h) * DD * TT + t0;
#pragma unroll
    for (int it = 0; it < 32; ++it) {
        int idx = tid + it * 256;
        int d = idx >> 6, tr = idx & 63;
        Vt[vb + (size_t)d * TT + tr] = vt[tr][d];
    }
}

// ---------------- causal flash attention: 4 waves x 32 q-rows, KVBLK=64 ----------------
// Round-5 schedule (512 uniform blocks, strip-pair (x,15-x), 2-phase dbuf K staging)
// + swapped QK^T: S^T = mfma(K,Q) puts each q-row's scores lane-local
//   (row = lane&15, 16 k-vals in regs) -> in-reg reduce + 2 shfl_xor, packed b64 P writes.
#define KV 64
#define PST 68

__global__ __launch_bounds__(256, 2) void k_attn(const u16* __restrict__ Q,
                                                 const u16* __restrict__ K,
                                                 const u16* __restrict__ Vt,
                                                 u16* __restrict__ AO) {
    const int fid = blockIdx.x + 8 * blockIdx.y + 128 * blockIdx.z;
    const int xg = fid >> 6;                // 0..7  (strip-pair index)
    const int hb = fid & 63;
    const int h = hb & 15, b = hb >> 4;

    const int tid = threadIdx.x, w = tid >> 6, l = tid & 63;
    const int lr = l & 15, lg = l >> 4;
    const size_t bh = (size_t)(b * HH + h);
    const u16* Qh = Q + bh * TT * DD;
    const u16* Kh = K + bh * TT * DD;
    const u16* Vh = Vt + bh * DD * TT;

    __shared__ __align__(16) u16 sK[2][KV * DD];    // 32 KB, double-buffered, XOR-swizzled
    __shared__ __align__(16) u16 sP[4][32 * PST];   // 17 KB, per-wave P tiles
    u16* myP = sP[w];

    const int strow = tid >> 4;       // staging sub-row 0..15
    const int sc16  = tid & 15;       // staging 16B-column

    for (int rep = 0; rep < 2; ++rep) {
        const int g = rep ? (15 - xg) : xg;     // strip-group (128 rows)
        const int q0w = g * 128 + w * 32;       // this wave's first q row
        const int nt = 2 * g + 2;               // k-tiles of 64

        sx8 qf[2][4];
#pragma unroll
        for (int i = 0; i < 2; i++)
#pragma unroll
            for (int kk = 0; kk < 4; kk++)
                qf[i][kk] = *(const sx8*)(Qh + (size_t)(q0w + i * 16 + lr) * DD + kk * 32 + lg * 8);

        f32x4 o[2][8] = {};
        float mrow[2] = {-1e30f, -1e30f};
        float lrow[2] = {0.0f, 0.0f};

        // prologue: stage tile 0 into buf 0 (linear dest, inverse-swizzled source)
#pragma unroll
        for (int i = 0; i < 4; ++i) {
            const int row = i * 16 + strow;
            const int scol = (sc16 ^ (row & 7)) * 8;
            __builtin_amdgcn_global_load_lds(
                (const __attribute__((address_space(1))) void*)(Kh + (size_t)row * DD + scol),
                (__attribute__((address_space(3))) void*)(&sK[0][i * 2048 + w * 512]),
                16, 0, 0);
        }
        __syncthreads();

        int cur = 0;
        for (int t = 0; t < nt; ++t) {
            const int k0 = t * KV;
            if (t + 1 < nt) {               // prefetch next K tile into buf^1
                const int kn = k0 + KV;
#pragma unroll
                for (int i = 0; i < 4; ++i) {
                    const int row = i * 16 + strow;
                    const int scol = (sc16 ^ (row & 7)) * 8;
                    __builtin_amdgcn_global_load_lds(
                        (const __attribute__((address_space(1))) void*)(Kh + (size_t)(kn + row) * DD + scol),
                        (__attribute__((address_space(3))) void*)(&sK[cur ^ 1][i * 2048 + w * 512]),
                        16, 0, 0);
                }
            }
            if (k0 <= q0w) {                // causally active for this wave
                // ---- S^T = K·Q^T from swizzled LDS: k on (lg,rg), q-row on lr ----
                f32x4 st[2][4] = {};
#pragma unroll
                for (int j = 0; j < 4; ++j) {
                    const int row = j * 16 + lr;
                    const int rx = row & 7;
                    sx8 kf[4];
#pragma unroll
                    for (int kk = 0; kk < 4; ++kk) {
                        const int c16 = (kk * 4 + lg) ^ rx;
                        kf[kk] = *(const sx8*)(&sK[cur][row * DD + c16 * 8]);
                    }
#pragma unroll
                    for (int kk = 0; kk < 4; ++kk) {
                        st[0][j] = mfma16(kf[kk], qf[0][kk], st[0][j]);
                        st[1][j] = mfma16(kf[kk], qf[1][kk], st[1][j]);
                    }
                }
                // ---- issue first-half V loads early (latency hides under softmax) ----
                sx8 vf0[8];
#pragma unroll
                for (int n = 0; n < 8; ++n)
                    vf0[n] = *(const sx8*)(Vh + (size_t)(n * 16 + lr) * TT + k0 + lg * 8);

                // ---- softmax: q-row lane-local; in-reg tree + 2 shfl_xor ----
                const bool need_mask = (k0 + 63 > q0w);
                const int klocal = lg * 4;          // this lane's k-subcolumn base
#pragma unroll
                for (int i = 0; i < 2; ++i) {
                    if (need_mask) {
                        const int cl = q0w + i * 16 + lr - k0;   // max allowed k-local
#pragma unroll
                        for (int j = 0; j < 4; ++j)
#pragma unroll
                            for (int rg = 0; rg < 4; ++rg)
                                if (j * 16 + klocal + rg > cl) st[i][j][rg] = -1e30f;
                    }
                    f32x4 m4;
#pragma unroll
                    for (int rg = 0; rg < 4; ++rg)
                        m4[rg] = fmaxf(fmaxf(st[i][0][rg], st[i][1][rg]),
                                       fmaxf(st[i][2][rg], st[i][3][rg]));
                    float pm = fmaxf(fmaxf(m4[0], m4[1]), fmaxf(m4[2], m4[3]));
                    pm = fmaxf(pm, __shfl_xor(pm, 16));
                    pm = fmaxf(pm, __shfl_xor(pm, 32));
                    const float mold = mrow[i];
                    const bool resc = pm > mold + 8.0f;     // defer-max (T13)
                    const float mnew = resc ? pm : mold;
                    mrow[i] = mnew;
                    float rs = 0.0f;
#pragma unroll
                    for (int j = 0; j < 4; ++j) {
                        float p0 = __expf(st[i][j][0] - mnew);
                        float p1 = __expf(st[i][j][1] - mnew);
                        float p2 = __expf(st[i][j][2] - mnew);
                        float p3 = __expf(st[i][j][3] - mnew);
                        rs += (p0 + p1) + (p2 + p3);
                        *(uint2*)(myP + (i * 16 + lr) * PST + j * 16 + klocal) =
                            make_uint2(pkbf(p0, p1), pkbf(p2, p3));
                    }
                    rs += __shfl_xor(rs, 16);
                    rs += __shfl_xor(rs, 32);
                    const float sf = resc ? __expf(mold - mnew) : 1.0f;
                    lrow[i] = lrow[i] * sf + rs;
                    if (__any(resc)) {                       // rare with defer-max
                        f32x4 sfo;
#pragma unroll
                        for (int rg = 0; rg < 4; ++rg)
                            sfo[rg] = __shfl(sf, 4 * lg + rg);
#pragma unroll
                        for (int n = 0; n < 8; ++n) o[i][n] *= sfo;
                    }
                }
                // ensure P writes landed before cross-lane reads (per-wave region)
                asm volatile("s_waitcnt lgkmcnt(0)" ::: "memory");
                __builtin_amdgcn_sched_barrier(0);

                // ---- PV: P as A-operand, V^T as B-operand ----
                sx8 pa0[2], pa1[2];
                pa0[0] = *(const sx8*)(myP + (size_t)lr * PST + lg * 8);
                pa0[1] = *(const sx8*)(myP + (size_t)(16 + lr) * PST + lg * 8);
                pa1[0] = *(const sx8*)(myP + (size_t)lr * PST + 32 + lg * 8);
                pa1[1] = *(const sx8*)(myP + (size_t)(16 + lr) * PST + 32 + lg * 8);
#pragma unroll
                for (int n = 0; n < 8; ++n) {
                    o[0][n] = mfma16(pa0[0], vf0[n], o[0][n]);
                    o[1][n] = mfma16(pa0[1], vf0[n], o[1][n]);
                }
#pragma unroll
                for (int n = 0; n < 8; ++n) {
                    sx8 vf1 = *(const sx8*)(Vh + (size_t)(n * 16 + lr) * TT + k0 + 32 + lg * 8);
                    o[0][n] = mfma16(pa1[0], vf1, o[0][n]);
                    o[1][n] = mfma16(pa1[1], vf1, o[1][n]);
                }
            }
            __syncthreads();    // drains vmcnt (prefetch done) + all waves done with sK[cur]
            cur ^= 1;
        }

        // ---- epilogue: fetch l for this lane's O-rows, write strip ----
#pragma unroll
        for (int i = 0; i < 2; ++i) {
            f32x4 linv;
#pragma unroll
            for (int rg = 0; rg < 4; ++rg)
                linv[rg] = __shfl(lrow[i], 4 * lg + rg);
#pragma unroll
            for (int rg = 0; rg < 4; ++rg) {
                const float inv = 1.0f / linv[rg];
                const int tq = q0w + i * 16 + lg * 4 + rg;
                u16* orow = AO + ((size_t)(b * TT) + tq) * CC + h * DD + lr;
#pragma unroll
                for (int n = 0; n < 8; ++n)
                    orow[n * 16] = f2bf(o[i][n][rg] * inv);
            }
        }
    }
}

extern "C" void kernel_launch(void* const* d_in, const int* in_sizes, int n_in,
                              void* d_out, int out_size, void* d_ws, size_t ws_size,
                              hipStream_t stream) {
    const float* x     = (const float*)d_in[0];
    const float* freqs = (const float*)d_in[1];
    // d_in[2] = mask: causal, implemented analytically
    const float* w_qkv = (const float*)d_in[3];
    const float* w_out = (const float*)d_in[4];
    float* out = (float*)d_out;

    u16* ws   = (u16*)d_ws;
    u16* xb   = ws;
    u16* wqb  = xb   + (size_t)MM * CC;
    u16* wob  = wqb  + (size_t)FF * CC;
    u16* qkvb = wob  + (size_t)CC * CC;
    u16* Qr   = qkvb + (size_t)MM * FF;
    u16* Kr   = Qr   + (size_t)MM * CC;
    u16* Vt   = Kr   + (size_t)MM * CC;
    u16* AO   = qkvb;                        // alias: qkv dead after k_rope

    k_cvt<<<MM * CC / 2048, 256, 0, stream>>>(x, xb, MM * CC / 8);
    k_cvt<<<FF * CC / 2048, 256, 0, stream>>>(w_qkv, wqb, FF * CC / 8);
    k_cvt<<<CC * CC / 2048, 256, 0, stream>>>(w_out, wob, CC * CC / 8);

    k_gemm<0><<<(MM / 256) * (FF / 256), 512, 0, stream>>>(xb, wqb, nullptr, qkvb, MM, FF, CC);
    k_rope<<<dim3(TT / 64, HH, BB), 256, 0, stream>>>(qkvb, freqs, Qr, Kr, Vt);
    k_attn<<<dim3(8, HH, BB), 256, 0, stream>>>(Qr, Kr, Vt, AO);
    k_gemm<1><<<(MM / 256) * (CC / 256), 512, 0, stream>>>(AO, wob, out, nullptr, MM, CC, CC);
}

// Round 13
// 520.365 us; speedup vs baseline: 1.0525x; 1.0525x over previous
//
#include <hip/hip_runtime.h>

typedef unsigned short u16;
typedef unsigned int   u32;

using sx8   = __attribute__((ext_vector_type(8))) short;   // 8 x bf16 bits
using f32x4 = __attribute__((ext_vector_type(4))) float;
using u16x8 = __attribute__((ext_vector_type(8))) unsigned short;

#define BB 4
#define TT 2048
#define CC 2048
#define HH 16
#define DD 128
#define FF 6144
#define MM 8192

static __device__ __forceinline__ u16 f2bf(float f) {
    u32 u = __builtin_bit_cast(u32, f);
    u32 lsb = (u >> 16) & 1u;
    u += 0x7fffu + lsb;
    return (u16)(u >> 16);
}
static __device__ __forceinline__ float bf2f(u16 b) {
    return __builtin_bit_cast(float, (u32)b << 16);
}
static __device__ __forceinline__ f32x4 mfma16(sx8 a, sx8 b, f32x4 c) {
    return __builtin_amdgcn_mfma_f32_16x16x32_bf16(a, b, c, 0, 0, 0);
}
static __device__ __forceinline__ u32 pkbf(float a, float b) {
    return (u32)f2bf(a) | ((u32)f2bf(b) << 16);
}

// ---------------- f32 -> bf16 convert, 8 elems/thread ----------------
__global__ __launch_bounds__(256) void k_cvt(const float* __restrict__ src,
                                             u16* __restrict__ dst, int n8) {
    int i = blockIdx.x * 256 + threadIdx.x;
    if (i >= n8) return;
    const float4* s = (const float4*)src;
    float4 a = s[2 * (size_t)i], b = s[2 * (size_t)i + 1];
    u16x8 r;
    r[0] = f2bf(a.x); r[1] = f2bf(a.y); r[2] = f2bf(a.z); r[3] = f2bf(a.w);
    r[4] = f2bf(b.x); r[5] = f2bf(b.y); r[6] = f2bf(b.z); r[7] = f2bf(b.w);
    *(u16x8*)(dst + 8 * (size_t)i) = r;
}

// ---------------- bf16 A(MxK) @ Bt(NxK)^T GEMM, m97 structure ----------------
// MODE 1: plain f32 C output (out-proj).
// MODE 2: fused epilogue — RoPE(Q,K) + QKV split + V transpose:
//   each 128-col tile = one head, one of Q/K/V (block-uniform).
//   RoPE pair partner via shfl_xor(1); Q pre-scaled by 1/sqrt(D);
//   V transposed through per-wave LDS (padded), coalesced 16B stores.
template <int MODE>
__global__ __launch_bounds__(256, 2) void k_gemm(const u16* __restrict__ A,
                                                 const u16* __restrict__ Bt,
                                                 float* __restrict__ Cf,
                                                 const float* __restrict__ freqs,
                                                 u16* __restrict__ Qo,
                                                 u16* __restrict__ Ko,
                                                 u16* __restrict__ Vt,
                                                 int M, int N, int K) {
    __shared__ __align__(16) u16 sA[128 * 32];
    __shared__ __align__(16) u16 sB[128 * 32];
    __shared__ __align__(16) u16 vT[4][64][17];     // MODE 2 V-transpose staging
    const int n0 = blockIdx.x * 128, m0 = blockIdx.y * 128;
    const int tid = threadIdx.x, w = tid >> 6, l = tid & 63;
    const int wm = w >> 1, wn = w & 1;
    const int lr = l & 15, lg = l >> 4;
    f32x4 acc[4][4] = {};

    const int idx0 = w * 128 + l;
    const int idx1 = idx0 + 64;
    const int ra0 = idx0 >> 2, ca0 = (idx0 & 3) * 8;
    const int ra1 = idx1 >> 2, ca1 = (idx1 & 3) * 8;
    const u16* Ar0 = A + (size_t)(m0 + ra0) * K + ca0;
    const u16* Ar1 = A + (size_t)(m0 + ra1) * K + ca1;
    const u16* Br0 = Bt + (size_t)(n0 + ra0) * K + ca0;
    const u16* Br1 = Bt + (size_t)(n0 + ra1) * K + ca1;
    u16* sAd0 = sA + (w * 2 + 0) * 512;
    u16* sAd1 = sA + (w * 2 + 1) * 512;
    u16* sBd0 = sB + (w * 2 + 0) * 512;
    u16* sBd1 = sB + (w * 2 + 1) * 512;

    for (int k0 = 0; k0 < K; k0 += 32) {
        __builtin_amdgcn_global_load_lds(
            (const __attribute__((address_space(1))) void*)(Ar0 + k0),
            (__attribute__((address_space(3))) void*)sAd0, 16, 0, 0);
        __builtin_amdgcn_global_load_lds(
            (const __attribute__((address_space(1))) void*)(Ar1 + k0),
            (__attribute__((address_space(3))) void*)sAd1, 16, 0, 0);
        __builtin_amdgcn_global_load_lds(
            (const __attribute__((address_space(1))) void*)(Br0 + k0),
            (__attribute__((address_space(3))) void*)sBd0, 16, 0, 0);
        __builtin_amdgcn_global_load_lds(
            (const __attribute__((address_space(1))) void*)(Br1 + k0),
            (__attribute__((address_space(3))) void*)sBd1, 16, 0, 0);
        __syncthreads();
        sx8 af[4], bfr[4];
#pragma unroll
        for (int i = 0; i < 4; i++)
            af[i] = *(const sx8*)(sA + (wm * 64 + i * 16 + lr) * 32 + lg * 8);
#pragma unroll
        for (int j = 0; j < 4; j++)
            bfr[j] = *(const sx8*)(sB + (wn * 64 + j * 16 + lr) * 32 + lg * 8);
#pragma unroll
        for (int i = 0; i < 4; i++)
#pragma unroll
            for (int j = 0; j < 4; j++)
                acc[i][j] = mfma16(af[i], bfr[j], acc[i][j]);
        __syncthreads();
    }

    if (MODE == 1) {
        // plain f32 epilogue: D row = (lane>>4)*4+reg, col = lane&15
#pragma unroll
        for (int i = 0; i < 4; i++) {
            const int mr = m0 + wm * 64 + i * 16 + lg * 4;
#pragma unroll
            for (int j = 0; j < 4; j++) {
                const int nc = n0 + wn * 64 + j * 16 + lr;
#pragma unroll
                for (int rg = 0; rg < 4; rg++)
                    Cf[(size_t)(mr + rg) * N + nc] = acc[i][j][rg];
            }
        }
    } else {
        // fused qkv epilogue
        const int b = m0 >> 11;                 // batch (block-uniform)
        const int t0blk = m0 & 2047;
        const int kind = n0 >> 11;              // 0=Q 1=K 2=V (block-uniform)
        const int h = (n0 & 2047) >> 7;         // head (block-uniform)
        const size_t bh = (size_t)(b * HH + h);
        if (kind < 2) {
            u16* dst = (kind == 0 ? Qo : Ko) + bh * (size_t)(TT * DD);
            const float qs = (kind == 0) ? 0.08838834764831845f : 1.0f;
#pragma unroll
            for (int i = 0; i < 4; i++) {
#pragma unroll
                for (int j = 0; j < 4; j++) {
                    const int d = wn * 64 + j * 16 + lr;       // 0..127
                    const int dp2 = (d >> 1) * 2;
#pragma unroll
                    for (int rg = 0; rg < 4; rg++) {
                        const int t = t0blk + wm * 64 + i * 16 + lg * 4 + rg;
                        float v = acc[i][j][rg];
                        float p = __shfl_xor(v, 1);
                        float2 cs = *(const float2*)(freqs + (size_t)t * DD + dp2);
                        float r = (lr & 1) ? (p * cs.y + v * cs.x)
                                           : (v * cs.x - p * cs.y);
                        dst[(size_t)t * DD + d] = f2bf(r * qs);
                    }
                }
            }
        } else {
            u16* dstV = Vt + bh * (size_t)(DD * TT);
            const int t0w = t0blk + wm * 64;
            const int dl = l >> 2, seg = l & 3;
#pragma unroll
            for (int j = 0; j < 4; ++j) {
#pragma unroll
                for (int i = 0; i < 4; ++i)
#pragma unroll
                    for (int rg = 0; rg < 4; ++rg)
                        vT[w][i * 16 + lg * 4 + rg][lr] = f2bf(acc[i][j][rg]);
                asm volatile("s_waitcnt lgkmcnt(0)" ::: "memory");
                __builtin_amdgcn_sched_barrier(0);
                u16x8 t2[2];
#pragma unroll
                for (int jj = 0; jj < 16; ++jj)
                    t2[jj >> 3][jj & 7] = vT[w][seg * 16 + jj][dl];
                const int dg = wn * 64 + j * 16 + dl;
                u16* orow = dstV + (size_t)dg * TT + t0w + seg * 16;
                *(u16x8*)orow = t2[0];
                *((u16x8*)orow + 1) = t2[1];
                asm volatile("s_waitcnt lgkmcnt(0)" ::: "memory");   // reads done before next j overwrites
                __builtin_amdgcn_sched_barrier(0);
            }
        }
    }
}

// ---------------- causal flash attention: 4 waves x 32 q-rows, KVBLK=64 ----------------
// Round-5 schedule (512 uniform blocks, strip-pair (x,15-x), 2-phase dbuf K staging)
// + swapped QK^T: S^T = mfma(K,Q) puts each q-row's scores lane-local
//   (row = lane&15, 16 k-vals in regs) -> in-reg reduce + 2 shfl_xor, packed b64 P writes.
#define KV 64
#define PST 68

__global__ __launch_bounds__(256, 2) void k_attn(const u16* __restrict__ Q,
                                                 const u16* __restrict__ K,
                                                 const u16* __restrict__ Vt,
                                                 u16* __restrict__ AO) {
    const int fid = blockIdx.x + 8 * blockIdx.y + 128 * blockIdx.z;
    const int xg = fid >> 6;                // 0..7  (strip-pair index)
    const int hb = fid & 63;
    const int h = hb & 15, b = hb >> 4;

    const int tid = threadIdx.x, w = tid >> 6, l = tid & 63;
    const int lr = l & 15, lg = l >> 4;
    const size_t bh = (size_t)(b * HH + h);
    const u16* Qh = Q + bh * TT * DD;
    const u16* Kh = K + bh * TT * DD;
    const u16* Vh = Vt + bh * DD * TT;

    __shared__ __align__(16) u16 sK[2][KV * DD];    // 32 KB, double-buffered, XOR-swizzled
    __shared__ __align__(16) u16 sP[4][32 * PST];   // 17 KB, per-wave P tiles
    u16* myP = sP[w];

    const int strow = tid >> 4;       // staging sub-row 0..15
    const int sc16  = tid & 15;       // staging 16B-column

    for (int rep = 0; rep < 2; ++rep) {
        const int g = rep ? (15 - xg) : xg;     // strip-group (128 rows)
        const int q0w = g * 128 + w * 32;       // this wave's first q row
        const int nt = 2 * g + 2;               // k-tiles of 64

        sx8 qf[2][4];
#pragma unroll
        for (int i = 0; i < 2; i++)
#pragma unroll
            for (int kk = 0; kk < 4; kk++)
                qf[i][kk] = *(const sx8*)(Qh + (size_t)(q0w + i * 16 + lr) * DD + kk * 32 + lg * 8);

        f32x4 o[2][8] = {};
        float mrow[2] = {-1e30f, -1e30f};
        float lrow[2] = {0.0f, 0.0f};

        // prologue: stage tile 0 into buf 0 (linear dest, inverse-swizzled source)
#pragma unroll
        for (int i = 0; i < 4; ++i) {
            const int row = i * 16 + strow;
            const int scol = (sc16 ^ (row & 7)) * 8;
            __builtin_amdgcn_global_load_lds(
                (const __attribute__((address_space(1))) void*)(Kh + (size_t)row * DD + scol),
                (__attribute__((address_space(3))) void*)(&sK[0][i * 2048 + w * 512]),
                16, 0, 0);
        }
        __syncthreads();

        int cur = 0;
        for (int t = 0; t < nt; ++t) {
            const int k0 = t * KV;
            if (t + 1 < nt) {               // prefetch next K tile into buf^1
                const int kn = k0 + KV;
#pragma unroll
                for (int i = 0; i < 4; ++i) {
                    const int row = i * 16 + strow;
                    const int scol = (sc16 ^ (row & 7)) * 8;
                    __builtin_amdgcn_global_load_lds(
                        (const __attribute__((address_space(1))) void*)(Kh + (size_t)(kn + row) * DD + scol),
                        (__attribute__((address_space(3))) void*)(&sK[cur ^ 1][i * 2048 + w * 512]),
                        16, 0, 0);
                }
            }
            if (k0 <= q0w) {                // causally active for this wave
                // ---- S^T = K·Q^T from swizzled LDS: k on (lg,rg), q-row on lr ----
                f32x4 st[2][4] = {};
#pragma unroll
                for (int j = 0; j < 4; ++j) {
                    const int row = j * 16 + lr;
                    const int rx = row & 7;
                    sx8 kf[4];
#pragma unroll
                    for (int kk = 0; kk < 4; ++kk) {
                        const int c16 = (kk * 4 + lg) ^ rx;
                        kf[kk] = *(const sx8*)(&sK[cur][row * DD + c16 * 8]);
                    }
#pragma unroll
                    for (int kk = 0; kk < 4; ++kk) {
                        st[0][j] = mfma16(kf[kk], qf[0][kk], st[0][j]);
                        st[1][j] = mfma16(kf[kk], qf[1][kk], st[1][j]);
                    }
                }
                // ---- issue first-half V loads early (latency hides under softmax) ----
                sx8 vf0[8];
#pragma unroll
                for (int n = 0; n < 8; ++n)
                    vf0[n] = *(const sx8*)(Vh + (size_t)(n * 16 + lr) * TT + k0 + lg * 8);

                // ---- softmax: q-row lane-local; in-reg tree + 2 shfl_xor ----
                const bool need_mask = (k0 + 63 > q0w);
                const int klocal = lg * 4;          // this lane's k-subcolumn base
#pragma unroll
                for (int i = 0; i < 2; ++i) {
                    if (need_mask) {
                        const int cl = q0w + i * 16 + lr - k0;   // max allowed k-local
#pragma unroll
                        for (int j = 0; j < 4; ++j)
#pragma unroll
                            for (int rg = 0; rg < 4; ++rg)
                                if (j * 16 + klocal + rg > cl) st[i][j][rg] = -1e30f;
                    }
                    f32x4 m4;
#pragma unroll
                    for (int rg = 0; rg < 4; ++rg)
                        m4[rg] = fmaxf(fmaxf(st[i][0][rg], st[i][1][rg]),
                                       fmaxf(st[i][2][rg], st[i][3][rg]));
                    float pm = fmaxf(fmaxf(m4[0], m4[1]), fmaxf(m4[2], m4[3]));
                    pm = fmaxf(pm, __shfl_xor(pm, 16));
                    pm = fmaxf(pm, __shfl_xor(pm, 32));
                    const float mold = mrow[i];
                    const bool resc = pm > mold + 8.0f;     // defer-max (T13)
                    const float mnew = resc ? pm : mold;
                    mrow[i] = mnew;
                    float rs = 0.0f;
#pragma unroll
                    for (int j = 0; j < 4; ++j) {
                        float p0 = __expf(st[i][j][0] - mnew);
                        float p1 = __expf(st[i][j][1] - mnew);
                        float p2 = __expf(st[i][j][2] - mnew);
                        float p3 = __expf(st[i][j][3] - mnew);
                        rs += (p0 + p1) + (p2 + p3);
                        *(uint2*)(myP + (i * 16 + lr) * PST + j * 16 + klocal) =
                            make_uint2(pkbf(p0, p1), pkbf(p2, p3));
                    }
                    rs += __shfl_xor(rs, 16);
                    rs += __shfl_xor(rs, 32);
                    const float sf = resc ? __expf(mold - mnew) : 1.0f;
                    lrow[i] = lrow[i] * sf + rs;
                    if (__any(resc)) {                       // rare with defer-max
                        f32x4 sfo;
#pragma unroll
                        for (int rg = 0; rg < 4; ++rg)
                            sfo[rg] = __shfl(sf, 4 * lg + rg);
#pragma unroll
                        for (int n = 0; n < 8; ++n) o[i][n] *= sfo;
                    }
                }
                // ensure P writes landed before cross-lane reads (per-wave region)
                asm volatile("s_waitcnt lgkmcnt(0)" ::: "memory");
                __builtin_amdgcn_sched_barrier(0);

                // ---- PV: P as A-operand, V^T as B-operand ----
                sx8 pa0[2], pa1[2];
                pa0[0] = *(const sx8*)(myP + (size_t)lr * PST + lg * 8);
                pa0[1] = *(const sx8*)(myP + (size_t)(16 + lr) * PST + lg * 8);
                pa1[0] = *(const sx8*)(myP + (size_t)lr * PST + 32 + lg * 8);
                pa1[1] = *(const sx8*)(myP + (size_t)(16 + lr) * PST + 32 + lg * 8);
#pragma unroll
                for (int n = 0; n < 8; ++n) {
                    o[0][n] = mfma16(pa0[0], vf0[n], o[0][n]);
                    o[1][n] = mfma16(pa0[1], vf0[n], o[1][n]);
                }
#pragma unroll
                for (int n = 0; n < 8; ++n) {
                    sx8 vf1 = *(const sx8*)(Vh + (size_t)(n * 16 + lr) * TT + k0 + 32 + lg * 8);
                    o[0][n] = mfma16(pa1[0], vf1, o[0][n]);
                    o[1][n] = mfma16(pa1[1], vf1, o[1][n]);
                }
            }
            __syncthreads();    // drains vmcnt (prefetch done) + all waves done with sK[cur]
            cur ^= 1;
        }

        // ---- epilogue: fetch l for this lane's O-rows, write strip ----
#pragma unroll
        for (int i = 0; i < 2; ++i) {
            f32x4 linv;
#pragma unroll
            for (int rg = 0; rg < 4; ++rg)
                linv[rg] = __shfl(lrow[i], 4 * lg + rg);
#pragma unroll
            for (int rg = 0; rg < 4; ++rg) {
                const float inv = 1.0f / linv[rg];
                const int tq = q0w + i * 16 + lg * 4 + rg;
                u16* orow = AO + ((size_t)(b * TT) + tq) * CC + h * DD + lr;
#pragma unroll
                for (int n = 0; n < 8; ++n)
                    orow[n * 16] = f2bf(o[i][n][rg] * inv);
            }
        }
    }
}

extern "C" void kernel_launch(void* const* d_in, const int* in_sizes, int n_in,
                              void* d_out, int out_size, void* d_ws, size_t ws_size,
                              hipStream_t stream) {
    const float* x     = (const float*)d_in[0];
    const float* freqs = (const float*)d_in[1];
    // d_in[2] = mask: causal, implemented analytically
    const float* w_qkv = (const float*)d_in[3];
    const float* w_out = (const float*)d_in[4];
    float* out = (float*)d_out;

    u16* ws   = (u16*)d_ws;
    u16* xb   = ws;
    u16* wqb  = xb   + (size_t)MM * CC;
    u16* wob  = wqb  + (size_t)FF * CC;
    u16* AO   = wob  + (size_t)CC * CC;      // attn output (b,t,h*d)
    u16* Qr   = AO   + (size_t)MM * CC;
    u16* Kr   = Qr   + (size_t)MM * CC;
    u16* Vt   = Kr   + (size_t)MM * CC;

    k_cvt<<<MM * CC / 2048, 256, 0, stream>>>(x, xb, MM * CC / 8);
    k_cvt<<<FF * CC / 2048, 256, 0, stream>>>(w_qkv, wqb, FF * CC / 8);
    k_cvt<<<CC * CC / 2048, 256, 0, stream>>>(w_out, wob, CC * CC / 8);

    // gemm0 with fused RoPE/split/V^T epilogue (k_rope eliminated)
    k_gemm<2><<<dim3(FF / 128, MM / 128), 256, 0, stream>>>(
        xb, wqb, nullptr, freqs, Qr, Kr, Vt, MM, FF, CC);
    k_attn<<<dim3(8, HH, BB), 256, 0, stream>>>(Qr, Kr, Vt, AO);
    k_gemm<1><<<dim3(CC / 128, MM / 128), 256, 0, stream>>>(
        AO, wob, out, nullptr, nullptr, nullptr, nullptr, MM, CC, CC);
}